// Round 15
// baseline (473.170 us; speedup 1.0000x reference)
//
#include <hip/hip_runtime.h>
#include <hip/hip_bf16.h>
#include <stdint.h>

typedef unsigned int u32;
typedef unsigned short u16;
typedef short short8 __attribute__((ext_vector_type(8)));
typedef float f32x4 __attribute__((ext_vector_type(4)));
typedef unsigned short u16x4 __attribute__((ext_vector_type(4)));
typedef __attribute__((address_space(1))) const u32 gu32;
typedef __attribute__((address_space(3))) u32 lu32;

#define NN 50000
#define NNP 50048   // padded rows (391*128) so GEMM stores are unconditional
#define NE 200000
#define WCT 576     // 256 fsrc | 256 res | 8 e_src | 8 e_dst | 48 pad (cols of C)

__device__ __forceinline__ float leaky(float x){ return x >= 0.f ? x : 0.2f*x; }
__device__ __forceinline__ float bf2f(u16 u){ return __uint_as_float(((u32)u)<<16); }
__device__ __forceinline__ u16 f2bf(float f){            // RNE
    u32 u = __float_as_uint(f);
    u32 r = (u + 0x7fffu + ((u>>16)&1u)) >> 16;
    return (u16)r;
}
// pack 2 floats -> 2 bf16 (truncation) in ONE v_perm_b32
__device__ __forceinline__ u32 pack_bf2(float a, float b){
    return __builtin_amdgcn_perm(__float_as_uint(b), __float_as_uint(a), 0x07060302u);
}
__device__ __forceinline__ int nt_src(int r){ return (r==0)?0:((r==3)?2:1); }
__device__ __forceinline__ int nt_dst(int r){ return (r==1)?0:((r==2)?2:1); }

// ra[r][512] = rel_emb[r] @ rel_W[r]
__global__ void k_ra(const float* __restrict__ rel_emb, const float* __restrict__ rel_W,
                     float* __restrict__ ra){
    int r = blockIdx.x;
    for (int j = threadIdx.x; j < 512; j += blockDim.x){
        float acc = 0.f;
        for (int i = 0; i < 64; i++) acc += rel_emb[r*64+i] * rel_W[(r*64+i)*512 + j];
        ra[r*512 + j] = acc;
    }
}

// Assemble WcatS: chunk-transposed bf16 layout matching linear global_load_lds staging:
//   WcatS[((r*9+tile)*32 + kc)*512 + nrow*8 + off] = W^T[n=tile*64+nrow][k=kc*8+off]
__global__ void k_wcat(const float* __restrict__ node_W, const float* __restrict__ res_W,
                       const float* __restrict__ ra, u16* __restrict__ WcatS){
    int g = blockIdx.x*blockDim.x + threadIdx.x;
    if (g >= 4*WCT*256) return;
    int r = g/147456; int rem = g%147456;
    int tile = rem/16384; int rem2 = rem%16384;
    int kc = rem2/512; int rem3 = rem2%512;
    int nrow = rem3>>3; int off = rem3&7;
    int n = tile*64 + nrow;
    int k = kc*8 + off;
    int s = nt_src(r), d = nt_dst(r);
    float v;
    if (n < 256) v = node_W[(s*256+k)*256 + n];
    else if (n < 512) v = res_W[(d*256+k)*256 + (n-256)];
    else if (n < 520){ // e_src weights: node_W[s]·ra[h, D:]
        int h = n-512; float a = 0.f;
        for (int dd = 0; dd < 32; dd++) a += node_W[(s*256+k)*256 + h*32+dd] * ra[r*512 + h*64+32+dd];
        v = a;
    } else if (n < 528){ // e_dst weights: node_W[d]·ra[h, :D]
        int h = n-520; float a = 0.f;
        for (int dd = 0; dd < 32; dd++) a += node_W[(d*256+k)*256 + h*32+dd] * ra[r*512 + h*64+dd];
        v = a;
    } else v = 0.f;
    WcatS[g] = f2bf(v);
}

// MFMA GEMM: 512-thread block = 128-row strip x ALL 576 N. A K-resident in regs;
// B async-staged (global_load_lds) double-buffered; counted vmcnt + RAW barrier
// (T4): stores stay in flight across the barrier, one barrier per tile.
// Issue order pinned with sched_barrier(0) so the vmcnt FIFO count is exact.
__launch_bounds__(512, 4)
__global__ void k_gemm(const float* __restrict__ feat, const u16* __restrict__ WcatS,
                       const float* __restrict__ res_b,
                       u16* __restrict__ fsrc, u16* __restrict__ resb,
                       float* __restrict__ e_comb){
    __shared__ uint4 lsB[4096];          // 2 x 32KB B double buffer
    const short8* lsB8 = (const short8*)lsB;

    int r = blockIdx.y;
    int row0 = blockIdx.x*128;
    const float* A = feat + (size_t)r*NN*256;
    const u16*   W = WcatS + (size_t)r*9*16384;

    int t = threadIdx.x;
    int w = t>>6, l = t&63;
    int wm = (w>>1)*32, wn = (w&1)*32;   // 8 waves: 4 row-bands x 2 col-halves
    int li = l & 15, lg = l >> 4;

    // ---- issue DMA for tile 0 FIRST (drained by prologue vmcnt(0))
    #pragma unroll
    for (int i = 0; i < 4; i++){
        int chunk = i*512 + t;
        __builtin_amdgcn_global_load_lds((gu32*)(W + (size_t)chunk*8),
                                         (lu32*)((char*)lsB + chunk*16), 16, 0, 0);
    }

    // ---- A fragments: direct global -> registers, K-resident (64 VGPR/lane)
    short8 afr[2][8];
    #pragma unroll
    for (int mt = 0; mt < 2; mt++){
        int grow = row0 + wm + mt*16 + li; if (grow > NN-1) grow = NN-1;
        const float* ap = A + (size_t)grow*256 + lg*8;
        #pragma unroll
        for (int kk = 0; kk < 8; kk++){
            f32x4 x = __builtin_nontemporal_load((const f32x4*)(ap + kk*32));
            f32x4 y = __builtin_nontemporal_load((const f32x4*)(ap + kk*32 + 4));
            short8 f;
            ((u32*)&f)[0] = pack_bf2(x.x, x.y);
            ((u32*)&f)[1] = pack_bf2(x.z, x.w);
            ((u32*)&f)[2] = pack_bf2(y.x, y.y);
            ((u32*)&f)[3] = pack_bf2(y.z, y.w);
            afr[mt][kk] = f;
        }
    }

    int d = nt_dst(r);
    // ---- bias preload, pinned so no compiler vmcnt-wait lands inside the loop
    float bias0[4], bias1[4];
    #pragma unroll
    for (int j = 0; j < 4; j++){
        bias0[j] = res_b[d*256 + j*64 + wn + li];
        bias1[j] = res_b[d*256 + j*64 + wn + 16 + li];
        asm volatile("" : "+v"(bias0[j]), "+v"(bias1[j]));
    }

    // ---- full drain + barrier: tile 0 staged, all preloads complete
    asm volatile("s_waitcnt vmcnt(0)" ::: "memory");
    __builtin_amdgcn_sched_barrier(0);
    __builtin_amdgcn_s_barrier();

    #pragma unroll
    for (int T = 0; T < 8; T++){
        int cur = T & 1;
        // issue DMA(T+1) into the other buffer (safe: barrier passed)
        {
            const u16* tb = W + (size_t)(T+1)*16384;
            char* lb = (char*)lsB + (cur^1)*32768;
            #pragma unroll
            for (int i = 0; i < 4; i++){
                int chunk = i*512 + t;
                __builtin_amdgcn_global_load_lds((gu32*)(tb + (size_t)chunk*8),
                                                 (lu32*)(lb + chunk*16), 16, 0, 0);
            }
        }
        // PIN: DMA issues must precede the stores below in the vmcnt FIFO,
        // else vmcnt(16) completes stores instead of the DMA (R14 bug).
        __builtin_amdgcn_sched_barrier(0);
        // compute tile T from buf[cur]
        f32x4 acc[2][2] = {};
        #pragma unroll
        for (int kk = 0; kk < 8; kk++){
            short8 bfr[2];
            #pragma unroll
            for (int nt = 0; nt < 2; nt++)
                bfr[nt] = lsB8[cur*2048 + (kk*4+lg)*64 + wn + nt*16 + li];
            #pragma unroll
            for (int mt = 0; mt < 2; mt++)
                #pragma unroll
                for (int nt = 0; nt < 2; nt++)
                    acc[mt][nt] = __builtin_amdgcn_mfma_f32_16x16x32_bf16(afr[mt][kk], bfr[nt], acc[mt][nt], 0,0,0);
        }
        // direct C stores, UNCONDITIONAL (rows padded to NNP) -> uniform vmcnt
        u16* base = (T < 4) ? fsrc : resb;
        int cb = (T & 3)*64 + wn;
        float b0 = (T >= 4) ? bias0[T-4] : 0.f;
        float b1 = (T >= 4) ? bias1[T-4] : 0.f;
        #pragma unroll
        for (int mt = 0; mt < 2; mt++)
            #pragma unroll
            for (int qq = 0; qq < 4; qq++){
                int row = row0 + wm + mt*16 + lg*4 + qq;
                size_t off = ((size_t)r*NNP + row)*256 + cb;
                base[off + li]      = f2bf(acc[mt][0][qq] + b0);
                base[off + 16 + li] = f2bf(acc[mt][1][qq] + b1);
            }
        // counted wait: completes st(T-1)[16] + DMA(T+1)[4]; st(T)[16] stays in flight
        asm volatile("s_waitcnt vmcnt(16)" ::: "memory");
        __builtin_amdgcn_sched_barrier(0);
        __builtin_amdgcn_s_barrier();
    }

    // ---- tile 8 (buf 0): e-columns 512..527 -> e_comb (64B-line stores)
    if (wn == 0){
        f32x4 acc[2] = {};
        #pragma unroll
        for (int kk = 0; kk < 8; kk++){
            short8 bfr = lsB8[(kk*4+lg)*64 + li];
            #pragma unroll
            for (int mt = 0; mt < 2; mt++)
                acc[mt] = __builtin_amdgcn_mfma_f32_16x16x32_bf16(afr[mt][kk], bfr, acc[mt], 0,0,0);
        }
        #pragma unroll
        for (int mt = 0; mt < 2; mt++)
            #pragma unroll
            for (int qq = 0; qq < 4; qq++){
                int row = row0 + wm + mt*16 + lg*4 + qq;
                e_comb[((size_t)r*NNP + row)*16 + li] = acc[mt][qq];
            }
    }
}

// ---- CSR build: count -> hierarchical scan -> scatter ----

__global__ void k_count(const int* __restrict__ dst_idx, u32* __restrict__ cnt){
    int r = blockIdx.y; int e = blockIdx.x*256 + threadIdx.x;
    if (e >= NE) return;
    atomicAdd(&cnt[r*NN + dst_idx[r*NE+e]], 1u);
}

__global__ void k_scan1(const u32* __restrict__ cnt, u32* __restrict__ bsum){
    int r = blockIdx.y, b = blockIdx.x;
    int i = b*256 + threadIdx.x;
    u32 v = (i < NN) ? cnt[r*NN+i] : 0u;
    #pragma unroll
    for (int off = 1; off < 64; off <<= 1) v += __shfl_xor(v, off, 64);
    __shared__ u32 wsum[4];
    int lane = threadIdx.x & 63, w = threadIdx.x >> 6;
    if (lane == 0) wsum[w] = v;
    __syncthreads();
    if (threadIdx.x == 0) bsum[r*256 + b] = wsum[0]+wsum[1]+wsum[2]+wsum[3];
}

__device__ __forceinline__ u32 block_scan_incl(u32 v){
    __shared__ u32 wsum[4];
    int lane = threadIdx.x & 63, w = threadIdx.x >> 6;
    #pragma unroll
    for (int off = 1; off < 64; off <<= 1){
        u32 t = __shfl_up(v, off, 64);
        if (lane >= off) v += t;
    }
    if (lane == 63) wsum[w] = v;
    __syncthreads();
    u32 add = 0;
    #pragma unroll
    for (int k = 0; k < 4; k++) if (k < w) add += wsum[k];
    return v + add;
}

__global__ void k_scan2(u32* __restrict__ bsum){
    int r = blockIdx.x;
    u32 v = bsum[r*256 + threadIdx.x];
    u32 incl = block_scan_incl(v);
    bsum[r*256 + threadIdx.x] = incl - v;
}

__global__ void k_scan3(const u32* __restrict__ cnt, const u32* __restrict__ bsum,
                        u32* __restrict__ row_ptr){
    int r = blockIdx.y, b = blockIdx.x;
    int i = b*256 + threadIdx.x;
    u32 v = (i < NN) ? cnt[r*NN+i] : 0u;
    u32 incl = block_scan_incl(v);
    if (i < NN) row_ptr[r*(NN+1) + i + 1] = bsum[r*256 + b] + incl;
    if (b == 0 && threadIdx.x == 0) row_ptr[r*(NN+1)] = 0u;
}

// per edge: pos in dst bucket; payload = src + 8 PRE-EXPONENTIATED logits
__global__ void k_scatter(const int* __restrict__ src_idx, const int* __restrict__ dst_idx,
                          const float* __restrict__ e_comb,
                          const u32* __restrict__ row_ptr, u32* __restrict__ cnt2,
                          u32* __restrict__ src_pack, float* __restrict__ e_pack){
    int r = blockIdx.y; int e = blockIdx.x*256 + threadIdx.x;
    if (e >= NE) return;
    int s = src_idx[r*NE+e], d = dst_idx[r*NE+e];
    u32 pos = row_ptr[r*(NN+1)+d] + atomicAdd(&cnt2[r*NN+d], 1u);
    src_pack[r*NE + pos] = (u32)s;
    const f32x4* es = (const f32x4*)(e_comb + ((size_t)r*NNP + s)*16);
    const f32x4* ed = (const f32x4*)(e_comb + ((size_t)r*NNP + d)*16 + 8);
    f32x4 s0 = es[0], s1 = es[1], d0 = ed[0], d1 = ed[1];
    f32x4 w0, w1;
    w0.x = __expf(leaky(s0.x+d0.x)); w0.y = __expf(leaky(s0.y+d0.y));
    w0.z = __expf(leaky(s0.z+d0.z)); w0.w = __expf(leaky(s0.w+d0.w));
    w1.x = __expf(leaky(s1.x+d1.x)); w1.y = __expf(leaky(s1.y+d1.y));
    w1.z = __expf(leaky(s1.z+d1.z)); w1.w = __expf(leaky(s1.w+d1.w));
    f32x4* ep = (f32x4*)(e_pack + ((size_t)(r*NE)+pos)*8);
    ep[0] = w0; ep[1] = w1;
}

// Shared aggregation core: per (node, relation) wave -> conv row (c0..c3 per lane).
__device__ __forceinline__ void agg_core(int n, int r, int l, int h,
                                         const u32* __restrict__ row_ptr,
                                         const u32* __restrict__ src_pack,
                                         const float* __restrict__ e_pack,
                                         const u16* __restrict__ fsrc,
                                         const u16* __restrict__ resb,
                                         const float* __restrict__ res_alpha,
                                         float& c0, float& c1, float& c2, float& c3){
    u32 p0 = row_ptr[r*(NN+1)+n];
    u32 p1 = row_ptr[r*(NN+1)+n+1];
    int deg = (int)(p1 - p0);

    // phase 1: plain sum of pre-exponentiated weights
    float s = 0.f;
    for (int i = (l>>3); i < deg; i += 8)
        s += e_pack[((size_t)(r*NE) + p0 + i)*8 + (l&7)];
    #pragma unroll
    for (int msk = 8; msk < 64; msk <<= 1)
        s += __shfl_xor(s, msk, 64);
    float sh = __shfl(s, h, 64);
    float inv_sh = (deg > 0) ? 1.0f / sh : 0.f;

    // phase 2: gather-accumulate; src preloaded + shfl-broadcast, 4-way unroll
    float a0=0.f, a1=0.f, a2=0.f, a3=0.f;
    const size_t ebase = (size_t)r*NE + p0;
    const u16* fbase = fsrc + (size_t)r*NNP*256;
    for (int base = 0; base < deg; base += 64){
        int rem = deg - base; if (rem > 64) rem = 64;
        u32 my_src = 0;
        if (l < rem) my_src = src_pack[ebase + base + l];
        int i = 0;
        for (; i+4 <= rem; i += 4){
            u32 s0 = __shfl(my_src, i, 64);
            u32 s1 = __shfl(my_src, i+1, 64);
            u32 s2 = __shfl(my_src, i+2, 64);
            u32 s3 = __shfl(my_src, i+3, 64);
            float ex0 = e_pack[(ebase + base + i)*8 + h];
            float ex1 = e_pack[(ebase + base + i + 1)*8 + h];
            float ex2 = e_pack[(ebase + base + i + 2)*8 + h];
            float ex3 = e_pack[(ebase + base + i + 3)*8 + h];
            ushort4 f0 = *(const ushort4*)(fbase + (size_t)s0*256 + l*4);
            ushort4 f1 = *(const ushort4*)(fbase + (size_t)s1*256 + l*4);
            ushort4 f2 = *(const ushort4*)(fbase + (size_t)s2*256 + l*4);
            ushort4 f3 = *(const ushort4*)(fbase + (size_t)s3*256 + l*4);
            float w0 = ex0*inv_sh, w1 = ex1*inv_sh, w2 = ex2*inv_sh, w3 = ex3*inv_sh;
            a0 += bf2f(f0.x)*w0 + bf2f(f1.x)*w1 + bf2f(f2.x)*w2 + bf2f(f3.x)*w3;
            a1 += bf2f(f0.y)*w0 + bf2f(f1.y)*w1 + bf2f(f2.y)*w2 + bf2f(f3.y)*w3;
            a2 += bf2f(f0.z)*w0 + bf2f(f1.z)*w1 + bf2f(f2.z)*w2 + bf2f(f3.z)*w3;
            a3 += bf2f(f0.w)*w0 + bf2f(f1.w)*w1 + bf2f(f2.w)*w2 + bf2f(f3.w)*w3;
        }
        for (; i < rem; i++){
            u32 s0 = __shfl(my_src, i, 64);
            float w0 = e_pack[(ebase + base + i)*8 + h]*inv_sh;
            ushort4 f0 = *(const ushort4*)(fbase + (size_t)s0*256 + l*4);
            a0 += bf2f(f0.x)*w0; a1 += bf2f(f0.y)*w0; a2 += bf2f(f0.z)*w0; a3 += bf2f(f0.w)*w0;
        }
    }

    int d = nt_dst(r);
    float alpha = 1.f/(1.f + __expf(-res_alpha[d]));
    float beta = 1.f - alpha;
    u16x4 rv = __builtin_nontemporal_load((const u16x4*)(resb + ((size_t)r*NNP+n)*256 + l*4));
    c0 = fmaxf(a0,0.f)*alpha + bf2f(rv.x)*beta;
    c1 = fmaxf(a1,0.f)*alpha + bf2f(rv.y)*beta;
    c2 = fmaxf(a2,0.f)*alpha + bf2f(rv.z)*beta;
    c3 = fmaxf(a3,0.f)*alpha + bf2f(rv.w)*beta;
}

// Pass 1: relations 1,2 (no cross-attention).
__launch_bounds__(128)
__global__ void k_agg12(const u32* __restrict__ row_ptr, const u32* __restrict__ src_pack,
                        const float* __restrict__ e_pack, const u16* __restrict__ fsrc,
                        const u16* __restrict__ resb, const float* __restrict__ res_alpha,
                        float* __restrict__ out){
    int n = blockIdx.x;
    int r = 1 + (threadIdx.x >> 6);   // 1 or 2
    int l = threadIdx.x & 63;
    int h = l >> 3;
    float c0, c1, c2, c3;
    agg_core(n, r, l, h, row_ptr, src_pack, e_pack, fsrc, resb, res_alpha, c0, c1, c2, c3);
    f32x4 o = {c0, c1, c2, c3};
    __builtin_nontemporal_store(o, (f32x4*)(out + ((size_t)r*NN+n)*256 + l*4));
}

// Pass 2: relations 0,3 + fused cross-attention (dst ntype 1 group).
__launch_bounds__(128)
__global__ void k_aggx03(const u32* __restrict__ row_ptr, const u32* __restrict__ src_pack,
                         const float* __restrict__ e_pack, const u16* __restrict__ fsrc,
                         const u16* __restrict__ resb, const float* __restrict__ res_alpha,
                         const float* __restrict__ cross_attn, float* __restrict__ out){
    __shared__ float cbuf[2][256];   // conv rows of relations 0 and 3
    __shared__ float dots[4][8];     // [c0·ca0, c0·ca3, c3·ca0, c3·ca3][head]

    int n = blockIdx.x;
    int w = threadIdx.x >> 6;        // 0 or 1
    int r = w ? 3 : 0;
    int l = threadIdx.x & 63;
    int h = l >> 3;
    float c0, c1, c2, c3;
    agg_core(n, r, l, h, row_ptr, src_pack, e_pack, fsrc, resb, res_alpha, c0, c1, c2, c3);

    int slot = w;
    cbuf[slot][l*4+0] = c0; cbuf[slot][l*4+1] = c1;
    cbuf[slot][l*4+2] = c2; cbuf[slot][l*4+3] = c3;
    const float* ca0 = cross_attn;            // relation 0 weights
    const float* ca3 = cross_attn + 3*256;    // relation 3 weights
    float d0 = c0*ca0[l*4+0] + c1*ca0[l*4+1] + c2*ca0[l*4+2] + c3*ca0[l*4+3];
    float d3 = c0*ca3[l*4+0] + c1*ca3[l*4+1] + c2*ca3[l*4+2] + c3*ca3[l*4+3];
    #pragma unroll
    for (int msk = 1; msk < 8; msk <<= 1){
        d0 += __shfl_xor(d0, msk, 64);
        d3 += __shfl_xor(d3, msk, 64);
    }
    if ((l & 7) == 0){
        dots[slot*2+0][h] = d0;
        dots[slot*2+1][h] = d3;
    }
    __syncthreads();
    // out r uses cross_attn[r]: logits = (conv0·ca_r, conv3·ca_r) per head
    float g0 = (r == 0) ? dots[0][h] : dots[1][h];
    float g3 = (r == 0) ? dots[2][h] : dots[3][h];
    g0 = leaky(g0); g3 = leaky(g3);
    float mm = fmaxf(g0, g3);
    float w0 = __expf(g0-mm), w3 = __expf(g3-mm);
    float inv = 1.f/(w0+w3);
    w0 *= inv; w3 *= inv;
    f32x4 o;
    o.x = w0*cbuf[0][l*4+0] + w3*cbuf[1][l*4+0];
    o.y = w0*cbuf[0][l*4+1] + w3*cbuf[1][l*4+1];
    o.z = w0*cbuf[0][l*4+2] + w3*cbuf[1][l*4+2];
    o.w = w0*cbuf[0][l*4+3] + w3*cbuf[1][l*4+3];
    __builtin_nontemporal_store(o, (f32x4*)(out + ((size_t)r*NN+n)*256 + l*4));
}

__global__ void k_relout(const float* __restrict__ rel_emb, const float* __restrict__ prop_W,
                         const float* __restrict__ prop_b, float* __restrict__ out){
    int r = blockIdx.x; int o = threadIdx.x;
    float acc = prop_b[r*256 + o];
    for (int i = 0; i < 64; i++) acc += rel_emb[r*64+i] * prop_W[(r*64+i)*256 + o];
    out[(size_t)4*NN*256 + r*256 + o] = acc;
}

extern "C" void kernel_launch(void* const* d_in, const int* in_sizes, int n_in,
                              void* d_out, int out_size, void* d_ws, size_t ws_size,
                              hipStream_t stream){
    const float* feat      = (const float*)d_in[0];
    const float* rel_emb   = (const float*)d_in[1];
    const float* node_W    = (const float*)d_in[2];
    const float* rel_W     = (const float*)d_in[3];
    const float* res_W     = (const float*)d_in[4];
    const float* res_b     = (const float*)d_in[5];
    const float* res_alpha = (const float*)d_in[6];
    const float* cross_attn= (const float*)d_in[7];
    const float* prop_W    = (const float*)d_in[8];
    const float* prop_b    = (const float*)d_in[9];
    const int* src_idx     = (const int*)d_in[10];
    const int* dst_idx     = (const int*)d_in[11];
    float* out = (float*)d_out;

    char* ws = (char*)d_ws;
    u32*   cnt     = (u32*)  (ws);                 //    800,000 B (4,NN)
    u32*   cnt2    = (u32*)  (ws + 800000);        //    800,000 B (4,NN)
    u32*   bsum    = (u32*)  (ws + 1600000);       //      4,096 B (4,256)
    u32*   row_ptr = (u32*)  (ws + 1604096);       //    800,016 B (4,NN+1)
    float* ra      = (float*)(ws + 2404112);       //      8,192 B (4,512)
    u16*   WcatS   = (u16*)  (ws + 2412304);       //  1,179,648 B (4,9,32,64,8) bf16
    float* e_comb  = (float*)(ws + 3591952);       // 12,812,288 B (4,NNP,16) [src|dst]
    u32*   src_pack= (u32*)  (ws + 16404240);      //  3,200,000 B (4,NE)
    float* e_pack  = (float*)(ws + 19604240);      // 25,600,000 B (4,NE,8)
    u16*   fsrc    = (u16*)  (ws + 45204240);      //102,498,304 B (4,NNP,256) bf16
    u16*   resb    = (u16*)  (ws + 147702544);     //102,498,304 B (4,NNP,256) bf16
    // total: 250,200,848 B

    hipMemsetAsync(cnt, 0, 1604096, stream);  // cnt + cnt2 + bsum

    k_ra<<<4, 256, 0, stream>>>(rel_emb, rel_W, ra);
    k_wcat<<<(4*WCT*256)/256, 256, 0, stream>>>(node_W, res_W, ra, WcatS);
    dim3 gg(NNP/128, 4);
    k_gemm<<<gg, 512, 0, stream>>>(feat, WcatS, res_b, fsrc, resb, e_comb);

    dim3 geg((NE+255)/256, 4);
    k_count<<<geg, 256, 0, stream>>>(dst_idx, cnt);
    dim3 gsc((NN+255)/256, 4);
    k_scan1<<<gsc, 256, 0, stream>>>(cnt, bsum);
    k_scan2<<<4, 256, 0, stream>>>(bsum);
    k_scan3<<<gsc, 256, 0, stream>>>(cnt, bsum, row_ptr);
    k_scatter<<<geg, 256, 0, stream>>>(src_idx, dst_idx, e_comb, row_ptr, cnt2,
                                       src_pack, e_pack);
    k_agg12<<<NN, 128, 0, stream>>>(row_ptr, src_pack, e_pack, fsrc, resb,
                                    res_alpha, out);
    k_aggx03<<<NN, 128, 0, stream>>>(row_ptr, src_pack, e_pack, fsrc, resb,
                                     res_alpha, cross_attn, out);
    k_relout<<<4, 256, 0, stream>>>(rel_emb, prop_W, prop_b, out);
}

// Round 16
// 415.556 us; speedup vs baseline: 1.1386x; 1.1386x over previous
//
#include <hip/hip_runtime.h>
#include <hip/hip_bf16.h>
#include <stdint.h>

typedef unsigned int u32;
typedef unsigned short u16;
typedef short short8 __attribute__((ext_vector_type(8)));
typedef float f32x4 __attribute__((ext_vector_type(4)));
typedef unsigned short u16x4 __attribute__((ext_vector_type(4)));
typedef __attribute__((address_space(1))) const u32 gu32;
typedef __attribute__((address_space(3))) u32 lu32;

#define NN 50000
#define NE 200000
#define WCT 576     // 256 fsrc | 256 res | 8 e_src | 8 e_dst | 48 pad (cols of C)

__device__ __forceinline__ float leaky(float x){ return x >= 0.f ? x : 0.2f*x; }
__device__ __forceinline__ float bf2f(u16 u){ return __uint_as_float(((u32)u)<<16); }
__device__ __forceinline__ u16 f2bf(float f){            // RNE
    u32 u = __float_as_uint(f);
    u32 r = (u + 0x7fffu + ((u>>16)&1u)) >> 16;
    return (u16)r;
}
// pack 2 floats -> 2 bf16 (truncation) in ONE v_perm_b32
__device__ __forceinline__ u32 pack_bf2(float a, float b){
    return __builtin_amdgcn_perm(__float_as_uint(b), __float_as_uint(a), 0x07060302u);
}
__device__ __forceinline__ int nt_src(int r){ return (r==0)?0:((r==3)?2:1); }
__device__ __forceinline__ int nt_dst(int r){ return (r==1)?0:((r==2)?2:1); }

// ra[r][512] = rel_emb[r] @ rel_W[r]
__global__ void k_ra(const float* __restrict__ rel_emb, const float* __restrict__ rel_W,
                     float* __restrict__ ra){
    int r = blockIdx.x;
    for (int j = threadIdx.x; j < 512; j += blockDim.x){
        float acc = 0.f;
        for (int i = 0; i < 64; i++) acc += rel_emb[r*64+i] * rel_W[(r*64+i)*512 + j];
        ra[r*512 + j] = acc;
    }
}

// Assemble WcatS: chunk-transposed bf16 layout matching linear global_load_lds staging:
//   WcatS[((r*9+tile)*32 + kc)*512 + nrow*8 + off] = W^T[n=tile*64+nrow][k=kc*8+off]
__global__ void k_wcat(const float* __restrict__ node_W, const float* __restrict__ res_W,
                       const float* __restrict__ ra, u16* __restrict__ WcatS){
    int g = blockIdx.x*blockDim.x + threadIdx.x;
    if (g >= 4*WCT*256) return;
    int r = g/147456; int rem = g%147456;
    int tile = rem/16384; int rem2 = rem%16384;
    int kc = rem2/512; int rem3 = rem2%512;
    int nrow = rem3>>3; int off = rem3&7;
    int n = tile*64 + nrow;
    int k = kc*8 + off;
    int s = nt_src(r), d = nt_dst(r);
    float v;
    if (n < 256) v = node_W[(s*256+k)*256 + n];
    else if (n < 512) v = res_W[(d*256+k)*256 + (n-256)];
    else if (n < 520){ // e_src weights: node_W[s]·ra[h, D:]
        int h = n-512; float a = 0.f;
        for (int dd = 0; dd < 32; dd++) a += node_W[(s*256+k)*256 + h*32+dd] * ra[r*512 + h*64+32+dd];
        v = a;
    } else if (n < 528){ // e_dst weights: node_W[d]·ra[h, :D]
        int h = n-520; float a = 0.f;
        for (int dd = 0; dd < 32; dd++) a += node_W[(d*256+k)*256 + h*32+dd] * ra[r*512 + h*64+dd];
        v = a;
    } else v = 0.f;
    WcatS[g] = f2bf(v);
}

// MFMA GEMM, fat blocks: one 512-thread block = 128-row strip x ALL 576 N.
// A K-resident in registers; B async-staged via global_load_lds, double-buffered.
// Epilogue C-stage ALIASES the dead B buffer -> LDS = 64 KB, 2 blocks/CU (16 waves).
__launch_bounds__(512, 4)
__global__ void k_gemm(const float* __restrict__ feat, const u16* __restrict__ WcatS,
                       const float* __restrict__ res_b,
                       u16* __restrict__ fsrc, u16* __restrict__ resb,
                       float* __restrict__ e_comb){
    __shared__ uint4 lsB[4096];          // 2 x 32KB B double buffer (cst aliases dead half)
    const short8* lsB8 = (const short8*)lsB;

    int r = blockIdx.y;
    int row0 = blockIdx.x*128;
    const float* A = feat + (size_t)r*NN*256;
    const u16*   W = WcatS + (size_t)r*9*16384;

    int t = threadIdx.x;
    int w = t>>6, l = t&63;
    int wm = (w>>1)*32, wn = (w&1)*32;   // 8 waves: 4 row-bands x 2 col-halves
    int li = l & 15, lg = l >> 4;

    // ---- A fragments: direct global -> registers, K-resident (64 VGPR/lane)
    short8 afr[2][8];
    #pragma unroll
    for (int mt = 0; mt < 2; mt++){
        int grow = row0 + wm + mt*16 + li; if (grow > NN-1) grow = NN-1;
        const float* ap = A + (size_t)grow*256 + lg*8;
        #pragma unroll
        for (int kk = 0; kk < 8; kk++){
            f32x4 x = __builtin_nontemporal_load((const f32x4*)(ap + kk*32));
            f32x4 y = __builtin_nontemporal_load((const f32x4*)(ap + kk*32 + 4));
            short8 f;
            ((u32*)&f)[0] = pack_bf2(x.x, x.y);
            ((u32*)&f)[1] = pack_bf2(x.z, x.w);
            ((u32*)&f)[2] = pack_bf2(y.x, y.y);
            ((u32*)&f)[3] = pack_bf2(y.z, y.w);
            afr[mt][kk] = f;
        }
    }

    // ---- prologue: stage tile 0 into buf 0 (async direct-to-LDS); 4 chunks/thread
    #pragma unroll
    for (int i = 0; i < 4; i++){
        int chunk = i*512 + t;
        __builtin_amdgcn_global_load_lds((gu32*)(W + (size_t)chunk*8),
                                         (lu32*)((char*)lsB + chunk*16), 16, 0, 0);
    }
    __syncthreads();

    int d = nt_dst(r);
    int orow = t>>2, oq = t&3;           // 512 threads -> 128 rows x 4 quarters
    int ogrow = row0 + orow;
    size_t onidx = (size_t)r*NN + ogrow;

    for (int T = 0; T < 8; T++){
        int cur = T & 1;
        // issue async stage of tile T+1 into the other buffer (flies under MFMA)
        {
            const u16* tb = W + (size_t)(T+1)*16384;
            char* lb = (char*)lsB + (cur^1)*32768;
            #pragma unroll
            for (int i = 0; i < 4; i++){
                int chunk = i*512 + t;
                __builtin_amdgcn_global_load_lds((gu32*)(tb + (size_t)chunk*8),
                                                 (lu32*)(lb + chunk*16), 16, 0, 0);
            }
        }
        // compute tile T from buf[cur]
        f32x4 acc[2][2] = {};
        #pragma unroll
        for (int kk = 0; kk < 8; kk++){
            short8 bfr[2];
            #pragma unroll
            for (int nt = 0; nt < 2; nt++)
                bfr[nt] = lsB8[cur*2048 + (kk*4+lg)*64 + wn + nt*16 + li];
            #pragma unroll
            for (int mt = 0; mt < 2; mt++)
                #pragma unroll
                for (int nt = 0; nt < 2; nt++)
                    acc[mt][nt] = __builtin_amdgcn_mfma_f32_16x16x32_bf16(afr[mt][kk], bfr[nt], acc[mt][nt], 0,0,0);
        }
        float bias[2] = {0.f, 0.f};
        if (T >= 4){
            bias[0] = res_b[d*256 + (T-4)*64 + wn + li];
            bias[1] = res_b[d*256 + (T-4)*64 + wn + 16 + li];
        }
        __syncthreads();   // ALL waves done reading buf[cur] (cst aliases it); drains async loads
        u16* cst = (u16*)(lsB + (size_t)cur*2048);   // 128 rows x stride 72 = 18.4 KB <= 32 KB
        #pragma unroll
        for (int mt = 0; mt < 2; mt++)
            #pragma unroll
            for (int nt = 0; nt < 2; nt++)
                #pragma unroll
                for (int qq = 0; qq < 4; qq++)
                    cst[(wm + mt*16 + lg*4 + qq)*72 + wn + nt*16 + li] = f2bf(acc[mt][nt][qq] + bias[nt]);
        __syncthreads();   // cst visible to all
        if (ogrow < NN){
            u16* dst = (T < 4) ? (fsrc + onidx*256 + T*64) : (resb + onidx*256 + (T-4)*64);
            const uint4* src = (const uint4*)(cst + orow*72 + oq*16);
            uint4* dq = (uint4*)(dst + oq*16);
            dq[0] = src[0];
            dq[1] = src[1];
        }
        __syncthreads();   // cst reads done before next iter's async loads overwrite buf[cur]
    }

    // ---- tile 8: e-columns 512..527 (nrow 0..15 of tile 8, in buf 0) -> e_comb
    if (wn == 0){
        f32x4 acc[2] = {};
        #pragma unroll
        for (int kk = 0; kk < 8; kk++){
            short8 bfr = lsB8[(kk*4+lg)*64 + li];
            #pragma unroll
            for (int mt = 0; mt < 2; mt++)
                acc[mt] = __builtin_amdgcn_mfma_f32_16x16x32_bf16(afr[mt][kk], bfr, acc[mt], 0,0,0);
        }
        #pragma unroll
        for (int mt = 0; mt < 2; mt++)
            #pragma unroll
            for (int qq = 0; qq < 4; qq++){
                int row = row0 + wm + mt*16 + lg*4 + qq;
                if (row < NN)
                    e_comb[((size_t)r*NN + row)*16 + li] = acc[mt][qq];
            }
    }
}

// ---- CSR build: count -> hierarchical scan -> scatter ----

__global__ void k_count(const int* __restrict__ dst_idx, u32* __restrict__ cnt){
    int r = blockIdx.y; int e = blockIdx.x*256 + threadIdx.x;
    if (e >= NE) return;
    atomicAdd(&cnt[r*NN + dst_idx[r*NE+e]], 1u);
}

__global__ void k_scan1(const u32* __restrict__ cnt, u32* __restrict__ bsum){
    int r = blockIdx.y, b = blockIdx.x;
    int i = b*256 + threadIdx.x;
    u32 v = (i < NN) ? cnt[r*NN+i] : 0u;
    #pragma unroll
    for (int off = 1; off < 64; off <<= 1) v += __shfl_xor(v, off, 64);
    __shared__ u32 wsum[4];
    int lane = threadIdx.x & 63, w = threadIdx.x >> 6;
    if (lane == 0) wsum[w] = v;
    __syncthreads();
    if (threadIdx.x == 0) bsum[r*256 + b] = wsum[0]+wsum[1]+wsum[2]+wsum[3];
}

__device__ __forceinline__ u32 block_scan_incl(u32 v){
    __shared__ u32 wsum[4];
    int lane = threadIdx.x & 63, w = threadIdx.x >> 6;
    #pragma unroll
    for (int off = 1; off < 64; off <<= 1){
        u32 t = __shfl_up(v, off, 64);
        if (lane >= off) v += t;
    }
    if (lane == 63) wsum[w] = v;
    __syncthreads();
    u32 add = 0;
    #pragma unroll
    for (int k = 0; k < 4; k++) if (k < w) add += wsum[k];
    return v + add;
}

__global__ void k_scan2(u32* __restrict__ bsum){
    int r = blockIdx.x;
    u32 v = bsum[r*256 + threadIdx.x];
    u32 incl = block_scan_incl(v);
    bsum[r*256 + threadIdx.x] = incl - v;
}

__global__ void k_scan3(const u32* __restrict__ cnt, const u32* __restrict__ bsum,
                        u32* __restrict__ row_ptr){
    int r = blockIdx.y, b = blockIdx.x;
    int i = b*256 + threadIdx.x;
    u32 v = (i < NN) ? cnt[r*NN+i] : 0u;
    u32 incl = block_scan_incl(v);
    if (i < NN) row_ptr[r*(NN+1) + i + 1] = bsum[r*256 + b] + incl;
    if (b == 0 && threadIdx.x == 0) row_ptr[r*(NN+1)] = 0u;
}

// per edge: pos in dst bucket; payload = src + 8 PRE-EXPONENTIATED logits
// (exp without max-subtraction is safe: |logit| <~ 20 << 88 at this data scale)
__global__ void k_scatter(const int* __restrict__ src_idx, const int* __restrict__ dst_idx,
                          const float* __restrict__ e_comb,
                          const u32* __restrict__ row_ptr, u32* __restrict__ cnt2,
                          u32* __restrict__ src_pack, float* __restrict__ e_pack){
    int r = blockIdx.y; int e = blockIdx.x*256 + threadIdx.x;
    if (e >= NE) return;
    int s = src_idx[r*NE+e], d = dst_idx[r*NE+e];
    u32 pos = row_ptr[r*(NN+1)+d] + atomicAdd(&cnt2[r*NN+d], 1u);
    src_pack[r*NE + pos] = (u32)s;
    const f32x4* es = (const f32x4*)(e_comb + (size_t)(r*NN+s)*16);
    const f32x4* ed = (const f32x4*)(e_comb + (size_t)(r*NN+d)*16 + 8);
    f32x4 s0 = es[0], s1 = es[1], d0 = ed[0], d1 = ed[1];
    f32x4 w0, w1;
    w0.x = __expf(leaky(s0.x+d0.x)); w0.y = __expf(leaky(s0.y+d0.y));
    w0.z = __expf(leaky(s0.z+d0.z)); w0.w = __expf(leaky(s0.w+d0.w));
    w1.x = __expf(leaky(s1.x+d1.x)); w1.y = __expf(leaky(s1.y+d1.y));
    w1.z = __expf(leaky(s1.z+d1.z)); w1.w = __expf(leaky(s1.w+d1.w));
    f32x4* ep = (f32x4*)(e_pack + ((size_t)(r*NE)+pos)*8);
    ep[0] = w0; ep[1] = w1;
}

// Shared aggregation core, SINGLE PASS: accumulate unnormalized a_j = sum ex_i*f_ij
// and the denominator s = sum ex_i in-lane (each lane sees every edge for its head),
// normalize at the end. No phase-1 sweep, no cross-lane shuffles.
__device__ __forceinline__ void agg_core(int n, int r, int l, int h,
                                         const u32* __restrict__ row_ptr,
                                         const u32* __restrict__ src_pack,
                                         const float* __restrict__ e_pack,
                                         const u16* __restrict__ fsrc,
                                         const u16* __restrict__ resb,
                                         const float* __restrict__ res_alpha,
                                         float& c0, float& c1, float& c2, float& c3){
    u32 p0 = row_ptr[r*(NN+1)+n];
    u32 p1 = row_ptr[r*(NN+1)+n+1];
    int deg = (int)(p1 - p0);

    float s = 0.f;
    float a0=0.f, a1=0.f, a2=0.f, a3=0.f;
    const size_t ebase = (size_t)r*NE + p0;
    const u16* fbase = fsrc + (size_t)r*NN*256;
    for (int base = 0; base < deg; base += 64){
        int rem = deg - base; if (rem > 64) rem = 64;
        u32 my_src = 0;
        if (l < rem) my_src = src_pack[ebase + base + l];
        int i = 0;
        for (; i+4 <= rem; i += 4){
            u32 s0 = __shfl(my_src, i, 64);
            u32 s1 = __shfl(my_src, i+1, 64);
            u32 s2 = __shfl(my_src, i+2, 64);
            u32 s3 = __shfl(my_src, i+3, 64);
            float ex0 = e_pack[(ebase + base + i)*8 + h];
            float ex1 = e_pack[(ebase + base + i + 1)*8 + h];
            float ex2 = e_pack[(ebase + base + i + 2)*8 + h];
            float ex3 = e_pack[(ebase + base + i + 3)*8 + h];
            ushort4 f0 = *(const ushort4*)(fbase + (size_t)s0*256 + l*4);
            ushort4 f1 = *(const ushort4*)(fbase + (size_t)s1*256 + l*4);
            ushort4 f2 = *(const ushort4*)(fbase + (size_t)s2*256 + l*4);
            ushort4 f3 = *(const ushort4*)(fbase + (size_t)s3*256 + l*4);
            s += ex0 + ex1 + ex2 + ex3;
            a0 += bf2f(f0.x)*ex0 + bf2f(f1.x)*ex1 + bf2f(f2.x)*ex2 + bf2f(f3.x)*ex3;
            a1 += bf2f(f0.y)*ex0 + bf2f(f1.y)*ex1 + bf2f(f2.y)*ex2 + bf2f(f3.y)*ex3;
            a2 += bf2f(f0.z)*ex0 + bf2f(f1.z)*ex1 + bf2f(f2.z)*ex2 + bf2f(f3.z)*ex3;
            a3 += bf2f(f0.w)*ex0 + bf2f(f1.w)*ex1 + bf2f(f2.w)*ex2 + bf2f(f3.w)*ex3;
        }
        for (; i < rem; i++){
            u32 s0 = __shfl(my_src, i, 64);
            float ex0 = e_pack[(ebase + base + i)*8 + h];
            ushort4 f0 = *(const ushort4*)(fbase + (size_t)s0*256 + l*4);
            s += ex0;
            a0 += bf2f(f0.x)*ex0; a1 += bf2f(f0.y)*ex0; a2 += bf2f(f0.z)*ex0; a3 += bf2f(f0.w)*ex0;
        }
    }
    float inv_sh = (deg > 0) ? 1.0f / s : 0.f;

    int d = nt_dst(r);
    float alpha = 1.f/(1.f + __expf(-res_alpha[d]));
    float beta = 1.f - alpha;
    u16x4 rv = __builtin_nontemporal_load((const u16x4*)(resb + ((size_t)r*NN+n)*256 + l*4));
    c0 = fmaxf(a0*inv_sh,0.f)*alpha + bf2f(rv.x)*beta;
    c1 = fmaxf(a1*inv_sh,0.f)*alpha + bf2f(rv.y)*beta;
    c2 = fmaxf(a2*inv_sh,0.f)*alpha + bf2f(rv.z)*beta;
    c3 = fmaxf(a3*inv_sh,0.f)*alpha + bf2f(rv.w)*beta;
}

// Pass 1: relations 1,2 (no cross-attention).
__launch_bounds__(128)
__global__ void k_agg12(const u32* __restrict__ row_ptr, const u32* __restrict__ src_pack,
                        const float* __restrict__ e_pack, const u16* __restrict__ fsrc,
                        const u16* __restrict__ resb, const float* __restrict__ res_alpha,
                        float* __restrict__ out){
    int n = blockIdx.x;
    int r = 1 + (threadIdx.x >> 6);   // 1 or 2
    int l = threadIdx.x & 63;
    int h = l >> 3;
    float c0, c1, c2, c3;
    agg_core(n, r, l, h, row_ptr, src_pack, e_pack, fsrc, resb, res_alpha, c0, c1, c2, c3);
    f32x4 o = {c0, c1, c2, c3};
    __builtin_nontemporal_store(o, (f32x4*)(out + ((size_t)r*NN+n)*256 + l*4));
}

// Pass 2: relations 0,3 + fused cross-attention (dst ntype 1 group).
__launch_bounds__(128)
__global__ void k_aggx03(const u32* __restrict__ row_ptr, const u32* __restrict__ src_pack,
                         const float* __restrict__ e_pack, const u16* __restrict__ fsrc,
                         const u16* __restrict__ resb, const float* __restrict__ res_alpha,
                         const float* __restrict__ cross_attn, float* __restrict__ out){
    __shared__ float cbuf[2][256];   // conv rows of relations 0 and 3
    __shared__ float dots[4][8];     // [c0·ca0, c0·ca3, c3·ca0, c3·ca3][head]

    int n = blockIdx.x;
    int w = threadIdx.x >> 6;        // 0 or 1
    int r = w ? 3 : 0;
    int l = threadIdx.x & 63;
    int h = l >> 3;
    float c0, c1, c2, c3;
    agg_core(n, r, l, h, row_ptr, src_pack, e_pack, fsrc, resb, res_alpha, c0, c1, c2, c3);

    int slot = w;
    cbuf[slot][l*4+0] = c0; cbuf[slot][l*4+1] = c1;
    cbuf[slot][l*4+2] = c2; cbuf[slot][l*4+3] = c3;
    const float* ca0 = cross_attn;            // relation 0 weights
    const float* ca3 = cross_attn + 3*256;    // relation 3 weights
    float d0 = c0*ca0[l*4+0] + c1*ca0[l*4+1] + c2*ca0[l*4+2] + c3*ca0[l*4+3];
    float d3 = c0*ca3[l*4+0] + c1*ca3[l*4+1] + c2*ca3[l*4+2] + c3*ca3[l*4+3];
    #pragma unroll
    for (int msk = 1; msk < 8; msk <<= 1){
        d0 += __shfl_xor(d0, msk, 64);
        d3 += __shfl_xor(d3, msk, 64);
    }
    if ((l & 7) == 0){
        dots[slot*2+0][h] = d0;
        dots[slot*2+1][h] = d3;
    }
    __syncthreads();
    // out r uses cross_attn[r]: logits = (conv0·ca_r, conv3·ca_r) per head
    float g0 = (r == 0) ? dots[0][h] : dots[1][h];
    float g3 = (r == 0) ? dots[2][h] : dots[3][h];
    g0 = leaky(g0); g3 = leaky(g3);
    float mm = fmaxf(g0, g3);
    float w0 = __expf(g0-mm), w3 = __expf(g3-mm);
    float inv = 1.f/(w0+w3);
    w0 *= inv; w3 *= inv;
    f32x4 o;
    o.x = w0*cbuf[0][l*4+0] + w3*cbuf[1][l*4+0];
    o.y = w0*cbuf[0][l*4+1] + w3*cbuf[1][l*4+1];
    o.z = w0*cbuf[0][l*4+2] + w3*cbuf[1][l*4+2];
    o.w = w0*cbuf[0][l*4+3] + w3*cbuf[1][l*4+3];
    __builtin_nontemporal_store(o, (f32x4*)(out + ((size_t)r*NN+n)*256 + l*4));
}

__global__ void k_relout(const float* __restrict__ rel_emb, const float* __restrict__ prop_W,
                         const float* __restrict__ prop_b, float* __restrict__ out){
    int r = blockIdx.x; int o = threadIdx.x;
    float acc = prop_b[r*256 + o];
    for (int i = 0; i < 64; i++) acc += rel_emb[r*64+i] * prop_W[(r*64+i)*256 + o];
    out[(size_t)4*NN*256 + r*256 + o] = acc;
}

extern "C" void kernel_launch(void* const* d_in, const int* in_sizes, int n_in,
                              void* d_out, int out_size, void* d_ws, size_t ws_size,
                              hipStream_t stream){
    const float* feat      = (const float*)d_in[0];
    const float* rel_emb   = (const float*)d_in[1];
    const float* node_W    = (const float*)d_in[2];
    const float* rel_W     = (const float*)d_in[3];
    const float* res_W     = (const float*)d_in[4];
    const float* res_b     = (const float*)d_in[5];
    const float* res_alpha = (const float*)d_in[6];
    const float* cross_attn= (const float*)d_in[7];
    const float* prop_W    = (const float*)d_in[8];
    const float* prop_b    = (const float*)d_in[9];
    const int* src_idx     = (const int*)d_in[10];
    const int* dst_idx     = (const int*)d_in[11];
    float* out = (float*)d_out;

    char* ws = (char*)d_ws;
    u32*   cnt     = (u32*)  (ws);                 //    800,000 B (4,NN)
    u32*   cnt2    = (u32*)  (ws + 800000);        //    800,000 B (4,NN)
    u32*   bsum    = (u32*)  (ws + 1600000);       //      4,096 B (4,256)
    u32*   row_ptr = (u32*)  (ws + 1604096);       //    800,016 B (4,NN+1)
    float* ra      = (float*)(ws + 2404112);       //      8,192 B (4,512)
    u16*   WcatS   = (u16*)  (ws + 2412304);       //  1,179,648 B (4,9,32,64,8) bf16
    float* e_comb  = (float*)(ws + 3591952);       // 12,800,000 B (4,NN,16) [src|dst]
    u32*   src_pack= (u32*)  (ws + 16391952);      //  3,200,000 B (4,NE)
    float* e_pack  = (float*)(ws + 19591952);      // 25,600,000 B (4,NE,8)
    u16*   fsrc    = (u16*)  (ws + 45191952);      //102,400,000 B (4,NN,256) bf16
    u16*   resb    = (u16*)  (ws + 147591952);     //102,400,000 B (4,NN,256) bf16
    // total: 249,991,952 B

    hipMemsetAsync(cnt, 0, 1604096, stream);  // cnt + cnt2 + bsum

    k_ra<<<4, 256, 0, stream>>>(rel_emb, rel_W, ra);
    k_wcat<<<(4*WCT*256)/256, 256, 0, stream>>>(node_W, res_W, ra, WcatS);
    dim3 gg((NN+127)/128, 4);
    k_gemm<<<gg, 512, 0, stream>>>(feat, WcatS, res_b, fsrc, resb, e_comb);

    dim3 geg((NE+255)/256, 4);
    k_count<<<geg, 256, 0, stream>>>(dst_idx, cnt);
    dim3 gsc((NN+255)/256, 4);
    k_scan1<<<gsc, 256, 0, stream>>>(cnt, bsum);
    k_scan2<<<4, 256, 0, stream>>>(bsum);
    k_scan3<<<gsc, 256, 0, stream>>>(cnt, bsum, row_ptr);
    k_scatter<<<geg, 256, 0, stream>>>(src_idx, dst_idx, e_comb, row_ptr, cnt2,
                                       src_pack, e_pack);
    k_agg12<<<NN, 128, 0, stream>>>(row_ptr, src_pack, e_pack, fsrc, resb,
                                    res_alpha, out);
    k_aggx03<<<NN, 128, 0, stream>>>(row_ptr, src_pack, e_pack, fsrc, resb,
                                     res_alpha, cross_attn, out);
    k_relout<<<4, 256, 0, stream>>>(rel_emb, prop_W, prop_b, out);
}

// Round 17
// 403.212 us; speedup vs baseline: 1.1735x; 1.0306x over previous
//
#include <hip/hip_runtime.h>
#include <hip/hip_bf16.h>
#include <stdint.h>

typedef unsigned int u32;
typedef unsigned short u16;
typedef short short8 __attribute__((ext_vector_type(8)));
typedef float f32x4 __attribute__((ext_vector_type(4)));
typedef unsigned short u16x4 __attribute__((ext_vector_type(4)));
typedef __attribute__((address_space(1))) const u32 gu32;
typedef __attribute__((address_space(3))) u32 lu32;

#define NN 50000
#define NE 200000
#define WCT 576     // 256 fsrc | 256 res | 8 e_src | 8 e_dst | 48 pad (cols of C)

__device__ __forceinline__ float leaky(float x){ return x >= 0.f ? x : 0.2f*x; }
__device__ __forceinline__ float bf2f(u16 u){ return __uint_as_float(((u32)u)<<16); }
__device__ __forceinline__ u16 f2bf(float f){            // RNE
    u32 u = __float_as_uint(f);
    u32 r = (u + 0x7fffu + ((u>>16)&1u)) >> 16;
    return (u16)r;
}
// pack 2 floats -> 2 bf16 (truncation) in ONE v_perm_b32
__device__ __forceinline__ u32 pack_bf2(float a, float b){
    return __builtin_amdgcn_perm(__float_as_uint(b), __float_as_uint(a), 0x07060302u);
}
__device__ __forceinline__ int nt_src(int r){ return (r==0)?0:((r==3)?2:1); }
__device__ __forceinline__ int nt_dst(int r){ return (r==1)?0:((r==2)?2:1); }

// ra[r][512] = rel_emb[r] @ rel_W[r]
__global__ void k_ra(const float* __restrict__ rel_emb, const float* __restrict__ rel_W,
                     float* __restrict__ ra){
    int r = blockIdx.x;
    for (int j = threadIdx.x; j < 512; j += blockDim.x){
        float acc = 0.f;
        for (int i = 0; i < 64; i++) acc += rel_emb[r*64+i] * rel_W[(r*64+i)*512 + j];
        ra[r*512 + j] = acc;
    }
}

// Assemble WcatS in 32-col HALF-TILE chunk-transposed layout:
//   WcatS[(((r*18 + s)*32 + kc)*32 + nrow)*8 + off] = W^T[n=s*32+nrow][k=kc*8+off]
__global__ void k_wcat(const float* __restrict__ node_W, const float* __restrict__ res_W,
                       const float* __restrict__ ra, u16* __restrict__ WcatS){
    int g = blockIdx.x*blockDim.x + threadIdx.x;
    if (g >= 4*WCT*256) return;
    int r = g/147456; int rem = g%147456;
    int s9 = rem/8192; int rem2 = rem%8192;
    int kc = rem2/256; int rem3 = rem2%256;
    int nrow = rem3>>3; int off = rem3&7;
    int n = s9*32 + nrow;
    int k = kc*8 + off;
    int s = nt_src(r), d = nt_dst(r);
    float v;
    if (n < 256) v = node_W[(s*256+k)*256 + n];
    else if (n < 512) v = res_W[(d*256+k)*256 + (n-256)];
    else if (n < 520){ // e_src weights: node_W[s]·ra[h, D:]
        int h = n-512; float a = 0.f;
        for (int dd = 0; dd < 32; dd++) a += node_W[(s*256+k)*256 + h*32+dd] * ra[r*512 + h*64+32+dd];
        v = a;
    } else if (n < 528){ // e_dst weights: node_W[d]·ra[h, :D]
        int h = n-520; float a = 0.f;
        for (int dd = 0; dd < 32; dd++) a += node_W[(d*256+k)*256 + h*32+dd] * ra[r*512 + h*64+dd];
        v = a;
    } else v = 0.f;
    WcatS[g] = f2bf(v);
}

// MFMA GEMM, high-occupancy: 512-thread block = 128-row strip x ALL 576 N,
// processed as 17 half-steps of 32 output cols. B half-tile (32n x 256k = 16KB)
// double-buffered (32 KB total LDS) -> 3 blocks/CU (24 waves). A K-resident.
// cst epilogue aliases the dead half-buffer.
__launch_bounds__(512, 6)
__global__ void k_gemm(const float* __restrict__ feat, const u16* __restrict__ WcatS,
                       const float* __restrict__ res_b,
                       u16* __restrict__ fsrc, u16* __restrict__ resb,
                       float* __restrict__ e_comb){
    __shared__ uint4 lsB[2048];          // 2 x 16KB half-tile dbuf (cst aliases dead half)
    const short8* lsB8 = (const short8*)lsB;

    int r = blockIdx.y;
    int row0 = blockIdx.x*128;
    const float* A = feat + (size_t)r*NN*256;
    const u16*   W = WcatS + (size_t)r*18*8192;

    int t = threadIdx.x;
    int w = t>>6, l = t&63;
    int wm = w*16;                        // 8 waves = 8 row-bands of 16
    int li = l & 15, lg = l >> 4;

    // ---- A fragments: rows wm+li, K-resident in regs (32 VGPR/lane)
    short8 afr[8];
    {
        int grow = row0 + wm + li; if (grow > NN-1) grow = NN-1;
        const float* ap = A + (size_t)grow*256 + lg*8;
        #pragma unroll
        for (int kk = 0; kk < 8; kk++){
            f32x4 x = __builtin_nontemporal_load((const f32x4*)(ap + kk*32));
            f32x4 y = __builtin_nontemporal_load((const f32x4*)(ap + kk*32 + 4));
            short8 f;
            ((u32*)&f)[0] = pack_bf2(x.x, x.y);
            ((u32*)&f)[1] = pack_bf2(x.z, x.w);
            ((u32*)&f)[2] = pack_bf2(y.x, y.y);
            ((u32*)&f)[3] = pack_bf2(y.z, y.w);
            afr[kk] = f;
        }
    }

    // ---- prologue: DMA half-tile 0 into buf 0 (1024 chunks, 2/thread)
    #pragma unroll
    for (int i = 0; i < 2; i++){
        int chunk = i*512 + t;
        __builtin_amdgcn_global_load_lds((gu32*)(W + (size_t)chunk*8),
                                         (lu32*)((char*)lsB + chunk*16), 16, 0, 0);
    }
    __syncthreads();

    int d = nt_dst(r);
    int orow = t>>2, oq = t&3;           // 512 threads -> 128 rows x 4 quarters(16B)
    int ogrow = row0 + orow;
    size_t onidx = (size_t)r*NN + ogrow;

    for (int s = 0; s < 17; s++){
        int cur = s & 1;
        if (s < 16){   // DMA next half-tile into the other buffer
            const u16* tb = W + (size_t)(s+1)*8192;
            char* lb = (char*)lsB + (cur^1)*16384;
            #pragma unroll
            for (int i = 0; i < 2; i++){
                int chunk = i*512 + t;
                __builtin_amdgcn_global_load_lds((gu32*)(tb + (size_t)chunk*8),
                                                 (lu32*)(lb + chunk*16), 16, 0, 0);
            }
        }
        // compute: 16 MFMA/wave over K=256
        f32x4 acc[2] = {};
        #pragma unroll
        for (int kk = 0; kk < 8; kk++){
            short8 b0 = lsB8[cur*1024 + (kk*4+lg)*32 + li];
            short8 b1 = lsB8[cur*1024 + (kk*4+lg)*32 + 16 + li];
            acc[0] = __builtin_amdgcn_mfma_f32_16x16x32_bf16(afr[kk], b0, acc[0], 0,0,0);
            acc[1] = __builtin_amdgcn_mfma_f32_16x16x32_bf16(afr[kk], b1, acc[1], 0,0,0);
        }
        if (s < 16){
            float bias[2] = {0.f, 0.f};
            if (s >= 8){
                bias[0] = res_b[d*256 + (s-8)*32 + li];
                bias[1] = res_b[d*256 + (s-8)*32 + 16 + li];
            }
            __syncthreads();   // B reads done (buf[cur] free); DMA(s+1) landed
            u16* cst = (u16*)(lsB + (size_t)cur*1024);   // 128 x stride36 = 9.2 KB
            #pragma unroll
            for (int nt = 0; nt < 2; nt++)
                #pragma unroll
                for (int qq = 0; qq < 4; qq++)
                    cst[(wm + lg*4 + qq)*36 + nt*16 + li] = f2bf(acc[nt][qq] + bias[nt]);
            __syncthreads();   // cst visible
            if (ogrow < NN){
                u16* dst = (s < 8) ? (fsrc + onidx*256 + s*32) : (resb + onidx*256 + (s-8)*32);
                *(uint4*)(dst + oq*8) = *(const uint4*)(cst + orow*36 + oq*8);
            }
            __syncthreads();   // cst reads done before next DMA overwrites buf[cur]
        } else {
            // s==16: cols 512..527 = nt0 frag -> e_comb (64B-line stores)
            #pragma unroll
            for (int qq = 0; qq < 4; qq++){
                int row = row0 + wm + lg*4 + qq;
                if (row < NN)
                    e_comb[((size_t)r*NN + row)*16 + li] = acc[0][qq];
            }
        }
    }
}

// ---- CSR build: count -> hierarchical scan -> scatter ----

__global__ void k_count(const int* __restrict__ dst_idx, u32* __restrict__ cnt){
    int r = blockIdx.y; int e = blockIdx.x*256 + threadIdx.x;
    if (e >= NE) return;
    atomicAdd(&cnt[r*NN + dst_idx[r*NE+e]], 1u);
}

__global__ void k_scan1(const u32* __restrict__ cnt, u32* __restrict__ bsum){
    int r = blockIdx.y, b = blockIdx.x;
    int i = b*256 + threadIdx.x;
    u32 v = (i < NN) ? cnt[r*NN+i] : 0u;
    #pragma unroll
    for (int off = 1; off < 64; off <<= 1) v += __shfl_xor(v, off, 64);
    __shared__ u32 wsum[4];
    int lane = threadIdx.x & 63, w = threadIdx.x >> 6;
    if (lane == 0) wsum[w] = v;
    __syncthreads();
    if (threadIdx.x == 0) bsum[r*256 + b] = wsum[0]+wsum[1]+wsum[2]+wsum[3];
}

__device__ __forceinline__ u32 block_scan_incl(u32 v){
    __shared__ u32 wsum[4];
    int lane = threadIdx.x & 63, w = threadIdx.x >> 6;
    #pragma unroll
    for (int off = 1; off < 64; off <<= 1){
        u32 t = __shfl_up(v, off, 64);
        if (lane >= off) v += t;
    }
    if (lane == 63) wsum[w] = v;
    __syncthreads();
    u32 add = 0;
    #pragma unroll
    for (int k = 0; k < 4; k++) if (k < w) add += wsum[k];
    return v + add;
}

__global__ void k_scan2(u32* __restrict__ bsum){
    int r = blockIdx.x;
    u32 v = bsum[r*256 + threadIdx.x];
    u32 incl = block_scan_incl(v);
    bsum[r*256 + threadIdx.x] = incl - v;
}

__global__ void k_scan3(const u32* __restrict__ cnt, const u32* __restrict__ bsum,
                        u32* __restrict__ row_ptr){
    int r = blockIdx.y, b = blockIdx.x;
    int i = b*256 + threadIdx.x;
    u32 v = (i < NN) ? cnt[r*NN+i] : 0u;
    u32 incl = block_scan_incl(v);
    if (i < NN) row_ptr[r*(NN+1) + i + 1] = bsum[r*256 + b] + incl;
    if (b == 0 && threadIdx.x == 0) row_ptr[r*(NN+1)] = 0u;
}

// per edge: pos in dst bucket; payload = src + 8 PRE-EXPONENTIATED logits
__global__ void k_scatter(const int* __restrict__ src_idx, const int* __restrict__ dst_idx,
                          const float* __restrict__ e_comb,
                          const u32* __restrict__ row_ptr, u32* __restrict__ cnt2,
                          u32* __restrict__ src_pack, float* __restrict__ e_pack){
    int r = blockIdx.y; int e = blockIdx.x*256 + threadIdx.x;
    if (e >= NE) return;
    int s = src_idx[r*NE+e], d = dst_idx[r*NE+e];
    u32 pos = row_ptr[r*(NN+1)+d] + atomicAdd(&cnt2[r*NN+d], 1u);
    src_pack[r*NE + pos] = (u32)s;
    const f32x4* es = (const f32x4*)(e_comb + (size_t)(r*NN+s)*16);
    const f32x4* ed = (const f32x4*)(e_comb + (size_t)(r*NN+d)*16 + 8);
    f32x4 s0 = es[0], s1 = es[1], d0 = ed[0], d1 = ed[1];
    f32x4 w0, w1;
    w0.x = __expf(leaky(s0.x+d0.x)); w0.y = __expf(leaky(s0.y+d0.y));
    w0.z = __expf(leaky(s0.z+d0.z)); w0.w = __expf(leaky(s0.w+d0.w));
    w1.x = __expf(leaky(s1.x+d1.x)); w1.y = __expf(leaky(s1.y+d1.y));
    w1.z = __expf(leaky(s1.z+d1.z)); w1.w = __expf(leaky(s1.w+d1.w));
    f32x4* ep = (f32x4*)(e_pack + ((size_t)(r*NE)+pos)*8);
    ep[0] = w0; ep[1] = w1;
}

// Shared aggregation core, SINGLE PASS: accumulate unnormalized a_j = sum ex_i*f_ij
// and the denominator s = sum ex_i in-lane, normalize at the end.
__device__ __forceinline__ void agg_core(int n, int r, int l, int h,
                                         const u32* __restrict__ row_ptr,
                                         const u32* __restrict__ src_pack,
                                         const float* __restrict__ e_pack,
                                         const u16* __restrict__ fsrc,
                                         const u16* __restrict__ resb,
                                         const float* __restrict__ res_alpha,
                                         float& c0, float& c1, float& c2, float& c3){
    u32 p0 = row_ptr[r*(NN+1)+n];
    u32 p1 = row_ptr[r*(NN+1)+n+1];
    int deg = (int)(p1 - p0);

    float s = 0.f;
    float a0=0.f, a1=0.f, a2=0.f, a3=0.f;
    const size_t ebase = (size_t)r*NE + p0;
    const u16* fbase = fsrc + (size_t)r*NN*256;
    for (int base = 0; base < deg; base += 64){
        int rem = deg - base; if (rem > 64) rem = 64;
        u32 my_src = 0;
        if (l < rem) my_src = src_pack[ebase + base + l];
        int i = 0;
        for (; i+4 <= rem; i += 4){
            u32 s0 = __shfl(my_src, i, 64);
            u32 s1 = __shfl(my_src, i+1, 64);
            u32 s2 = __shfl(my_src, i+2, 64);
            u32 s3 = __shfl(my_src, i+3, 64);
            float ex0 = e_pack[(ebase + base + i)*8 + h];
            float ex1 = e_pack[(ebase + base + i + 1)*8 + h];
            float ex2 = e_pack[(ebase + base + i + 2)*8 + h];
            float ex3 = e_pack[(ebase + base + i + 3)*8 + h];
            ushort4 f0 = *(const ushort4*)(fbase + (size_t)s0*256 + l*4);
            ushort4 f1 = *(const ushort4*)(fbase + (size_t)s1*256 + l*4);
            ushort4 f2 = *(const ushort4*)(fbase + (size_t)s2*256 + l*4);
            ushort4 f3 = *(const ushort4*)(fbase + (size_t)s3*256 + l*4);
            s += ex0 + ex1 + ex2 + ex3;
            a0 += bf2f(f0.x)*ex0 + bf2f(f1.x)*ex1 + bf2f(f2.x)*ex2 + bf2f(f3.x)*ex3;
            a1 += bf2f(f0.y)*ex0 + bf2f(f1.y)*ex1 + bf2f(f2.y)*ex2 + bf2f(f3.y)*ex3;
            a2 += bf2f(f0.z)*ex0 + bf2f(f1.z)*ex1 + bf2f(f2.z)*ex2 + bf2f(f3.z)*ex3;
            a3 += bf2f(f0.w)*ex0 + bf2f(f1.w)*ex1 + bf2f(f2.w)*ex2 + bf2f(f3.w)*ex3;
        }
        for (; i < rem; i++){
            u32 s0 = __shfl(my_src, i, 64);
            float ex0 = e_pack[(ebase + base + i)*8 + h];
            ushort4 f0 = *(const ushort4*)(fbase + (size_t)s0*256 + l*4);
            s += ex0;
            a0 += bf2f(f0.x)*ex0; a1 += bf2f(f0.y)*ex0; a2 += bf2f(f0.z)*ex0; a3 += bf2f(f0.w)*ex0;
        }
    }
    float inv_sh = (deg > 0) ? 1.0f / s : 0.f;

    int d = nt_dst(r);
    float alpha = 1.f/(1.f + __expf(-res_alpha[d]));
    float beta = 1.f - alpha;
    u16x4 rv = __builtin_nontemporal_load((const u16x4*)(resb + ((size_t)r*NN+n)*256 + l*4));
    c0 = fmaxf(a0*inv_sh,0.f)*alpha + bf2f(rv.x)*beta;
    c1 = fmaxf(a1*inv_sh,0.f)*alpha + bf2f(rv.y)*beta;
    c2 = fmaxf(a2*inv_sh,0.f)*alpha + bf2f(rv.z)*beta;
    c3 = fmaxf(a3*inv_sh,0.f)*alpha + bf2f(rv.w)*beta;
}

// Pass 1: relations 1,2 (no cross-attention).
__launch_bounds__(128)
__global__ void k_agg12(const u32* __restrict__ row_ptr, const u32* __restrict__ src_pack,
                        const float* __restrict__ e_pack, const u16* __restrict__ fsrc,
                        const u16* __restrict__ resb, const float* __restrict__ res_alpha,
                        float* __restrict__ out){
    int n = blockIdx.x;
    int r = 1 + (threadIdx.x >> 6);   // 1 or 2
    int l = threadIdx.x & 63;
    int h = l >> 3;
    float c0, c1, c2, c3;
    agg_core(n, r, l, h, row_ptr, src_pack, e_pack, fsrc, resb, res_alpha, c0, c1, c2, c3);
    f32x4 o = {c0, c1, c2, c3};
    __builtin_nontemporal_store(o, (f32x4*)(out + ((size_t)r*NN+n)*256 + l*4));
}

// Pass 2: relations 0,3 + fused cross-attention (dst ntype 1 group).
__launch_bounds__(128)
__global__ void k_aggx03(const u32* __restrict__ row_ptr, const u32* __restrict__ src_pack,
                         const float* __restrict__ e_pack, const u16* __restrict__ fsrc,
                         const u16* __restrict__ resb, const float* __restrict__ res_alpha,
                         const float* __restrict__ cross_attn, float* __restrict__ out){
    __shared__ float cbuf[2][256];   // conv rows of relations 0 and 3
    __shared__ float dots[4][8];     // [c0·ca0, c0·ca3, c3·ca0, c3·ca3][head]

    int n = blockIdx.x;
    int w = threadIdx.x >> 6;        // 0 or 1
    int r = w ? 3 : 0;
    int l = threadIdx.x & 63;
    int h = l >> 3;
    float c0, c1, c2, c3;
    agg_core(n, r, l, h, row_ptr, src_pack, e_pack, fsrc, resb, res_alpha, c0, c1, c2, c3);

    int slot = w;
    cbuf[slot][l*4+0] = c0; cbuf[slot][l*4+1] = c1;
    cbuf[slot][l*4+2] = c2; cbuf[slot][l*4+3] = c3;
    const float* ca0 = cross_attn;            // relation 0 weights
    const float* ca3 = cross_attn + 3*256;    // relation 3 weights
    float d0 = c0*ca0[l*4+0] + c1*ca0[l*4+1] + c2*ca0[l*4+2] + c3*ca0[l*4+3];
    float d3 = c0*ca3[l*4+0] + c1*ca3[l*4+1] + c2*ca3[l*4+2] + c3*ca3[l*4+3];
    #pragma unroll
    for (int msk = 1; msk < 8; msk <<= 1){
        d0 += __shfl_xor(d0, msk, 64);
        d3 += __shfl_xor(d3, msk, 64);
    }
    if ((l & 7) == 0){
        dots[slot*2+0][h] = d0;
        dots[slot*2+1][h] = d3;
    }
    __syncthreads();
    // out r uses cross_attn[r]: logits = (conv0·ca_r, conv3·ca_r) per head
    float g0 = (r == 0) ? dots[0][h] : dots[1][h];
    float g3 = (r == 0) ? dots[2][h] : dots[3][h];
    g0 = leaky(g0); g3 = leaky(g3);
    float mm = fmaxf(g0, g3);
    float w0 = __expf(g0-mm), w3 = __expf(g3-mm);
    float inv = 1.f/(w0+w3);
    w0 *= inv; w3 *= inv;
    f32x4 o;
    o.x = w0*cbuf[0][l*4+0] + w3*cbuf[1][l*4+0];
    o.y = w0*cbuf[0][l*4+1] + w3*cbuf[1][l*4+1];
    o.z = w0*cbuf[0][l*4+2] + w3*cbuf[1][l*4+2];
    o.w = w0*cbuf[0][l*4+3] + w3*cbuf[1][l*4+3];
    __builtin_nontemporal_store(o, (f32x4*)(out + ((size_t)r*NN+n)*256 + l*4));
}

__global__ void k_relout(const float* __restrict__ rel_emb, const float* __restrict__ prop_W,
                         const float* __restrict__ prop_b, float* __restrict__ out){
    int r = blockIdx.x; int o = threadIdx.x;
    float acc = prop_b[r*256 + o];
    for (int i = 0; i < 64; i++) acc += rel_emb[r*64+i] * prop_W[(r*64+i)*256 + o];
    out[(size_t)4*NN*256 + r*256 + o] = acc;
}

extern "C" void kernel_launch(void* const* d_in, const int* in_sizes, int n_in,
                              void* d_out, int out_size, void* d_ws, size_t ws_size,
                              hipStream_t stream){
    const float* feat      = (const float*)d_in[0];
    const float* rel_emb   = (const float*)d_in[1];
    const float* node_W    = (const float*)d_in[2];
    const float* rel_W     = (const float*)d_in[3];
    const float* res_W     = (const float*)d_in[4];
    const float* res_b     = (const float*)d_in[5];
    const float* res_alpha = (const float*)d_in[6];
    const float* cross_attn= (const float*)d_in[7];
    const float* prop_W    = (const float*)d_in[8];
    const float* prop_b    = (const float*)d_in[9];
    const int* src_idx     = (const int*)d_in[10];
    const int* dst_idx     = (const int*)d_in[11];
    float* out = (float*)d_out;

    char* ws = (char*)d_ws;
    u32*   cnt     = (u32*)  (ws);                 //    800,000 B (4,NN)
    u32*   cnt2    = (u32*)  (ws + 800000);        //    800,000 B (4,NN)
    u32*   bsum    = (u32*)  (ws + 1600000);       //      4,096 B (4,256)
    u32*   row_ptr = (u32*)  (ws + 1604096);       //    800,016 B (4,NN+1)
    float* ra      = (float*)(ws + 2404112);       //      8,192 B (4,512)
    u16*   WcatS   = (u16*)  (ws + 2412304);       //  1,179,648 B (4,18,32,32,8) bf16
    float* e_comb  = (float*)(ws + 3591952);       // 12,800,000 B (4,NN,16) [src|dst]
    u32*   src_pack= (u32*)  (ws + 16391952);      //  3,200,000 B (4,NE)
    float* e_pack  = (float*)(ws + 19591952);      // 25,600,000 B (4,NE,8)
    u16*   fsrc    = (u16*)  (ws + 45191952);      //102,400,000 B (4,NN,256) bf16
    u16*   resb    = (u16*)  (ws + 147591952);     //102,400,000 B (4,NN,256) bf16
    // total: 249,991,952 B

    hipMemsetAsync(cnt, 0, 1604096, stream);  // cnt + cnt2 + bsum

    k_ra<<<4, 256, 0, stream>>>(rel_emb, rel_W, ra);
    k_wcat<<<(4*WCT*256)/256, 256, 0, stream>>>(node_W, res_W, ra, WcatS);
    dim3 gg((NN+127)/128, 4);
    k_gemm<<<gg, 512, 0, stream>>>(feat, WcatS, res_b, fsrc, resb, e_comb);

    dim3 geg((NE+255)/256, 4);
    k_count<<<geg, 256, 0, stream>>>(dst_idx, cnt);
    dim3 gsc((NN+255)/256, 4);
    k_scan1<<<gsc, 256, 0, stream>>>(cnt, bsum);
    k_scan2<<<4, 256, 0, stream>>>(bsum);
    k_scan3<<<gsc, 256, 0, stream>>>(cnt, bsum, row_ptr);
    k_scatter<<<geg, 256, 0, stream>>>(src_idx, dst_idx, e_comb, row_ptr, cnt2,
                                       src_pack, e_pack);
    k_agg12<<<NN, 128, 0, stream>>>(row_ptr, src_pack, e_pack, fsrc, resb,
                                    res_alpha, out);
    k_aggx03<<<NN, 128, 0, stream>>>(row_ptr, src_pack, e_pack, fsrc, resb,
                                     res_alpha, cross_attn, out);
    k_relout<<<4, 256, 0, stream>>>(rel_emb, prop_W, prop_b, out);
}